// Round 1
// baseline (2954.787 us; speedup 1.0000x reference)
//
#include <hip/hip_runtime.h>
#include <stdint.h>

#define H_  8
#define D_  1024
#define DH_ 128
#define KD_ 3072
#define NS_ 2048
#define NK_ 8192
#define SCALE_ 0.08838834764831845f  // 1/sqrt(128)

typedef __bf16 bf16x8 __attribute__((ext_vector_type(8)));
typedef float  f32x4  __attribute__((ext_vector_type(4)));
typedef unsigned short u16;

__device__ __forceinline__ uint32_t pack_bf16_trunc(float a, float b) {
  uint32_t ua = __builtin_bit_cast(uint32_t, a);
  uint32_t ub = __builtin_bit_cast(uint32_t, b);
  return (ua >> 16) | (ub & 0xFFFF0000u);
}
__device__ __forceinline__ u16 f2bf_rne(float x) {
  uint32_t u = __builtin_bit_cast(uint32_t, x);
  u += 0x7FFFu + ((u >> 16) & 1u);
  return (u16)(u >> 16);
}
// async global->LDS, 16B/lane; LDS dest is wave-uniform base, HW adds lane*16B
__device__ __forceinline__ void gload_lds16(const void* g, void* l) {
  __builtin_amdgcn_global_load_lds(
      (const __attribute__((address_space(1))) uint32_t*)g,
      (__attribute__((address_space(3))) uint32_t*)l, 16, 0, 0);
}

// ---------------------------------------------------------------------------
// out[z][c][r] = bf16(in[z][r][c]); in [Z][R][C] fp32 -> out [Z][C][R] bf16
// grid (R/64, C/64, Z), block 256
__global__ __launch_bounds__(256) void transpose_cvt(
    const float* __restrict__ in, u16* __restrict__ out, int R, int C) {
  __shared__ float tile[64][65];
  const int z = blockIdx.z;
  const int r0 = blockIdx.x * 64, c0 = blockIdx.y * 64;
  const float* src = in + (size_t)z * R * C;
  u16* dst = out + (size_t)z * R * C;
  const int t = threadIdx.x;
#pragma unroll
  for (int j = 0; j < 4; ++j) {
    int q = t + 256 * j;
    int row = q >> 4;
    int c4 = (q & 15) * 4;
    const float4 v = *reinterpret_cast<const float4*>(src + (size_t)(r0 + row) * C + c0 + c4);
    tile[row][c4 + 0] = v.x; tile[row][c4 + 1] = v.y;
    tile[row][c4 + 2] = v.z; tile[row][c4 + 3] = v.w;
  }
  __syncthreads();
#pragma unroll
  for (int j = 0; j < 2; ++j) {
    int q = t + 256 * j;
    int row = q >> 3;  // c index
    int seg = q & 7;   // r segment
    u16 tmp[8];
#pragma unroll
    for (int i = 0; i < 8; ++i) tmp[i] = f2bf_rne(tile[seg * 8 + i][row]);
    *reinterpret_cast<int4*>(dst + (size_t)(c0 + row) * R + r0 + seg * 8) =
        *reinterpret_cast<const int4*>(tmp);
  }
}

// ---------------------------------------------------------------------------
// P[h][m][e] = bf16( sum_f A[m][f] * Wt[h][e][f] + bias[h][e] )
// A fp32 [M][F]; Wt bf16 [H][128][F]; grid (M/128, H), block 256
__global__ __launch_bounds__(256, 2) void proj_gemm(
    const float* __restrict__ A, const u16* __restrict__ Wt,
    const float* __restrict__ bias, u16* __restrict__ P, int M, int F) {
  __shared__ u16 lA[128 * 64];
  __shared__ u16 lB[128 * 64];
  const int h = blockIdx.y;
  const int m0 = blockIdx.x * 128;
  const u16* B = Wt + (size_t)h * 128 * F;
  const int t = threadIdx.x, lane = t & 63, w = t >> 6;
  const int wr = w >> 1, wc = w & 1;
  const int fr = lane & 15, quad = lane >> 4;
  f32x4 acc[4][4];
  const f32x4 z4 = {0.f, 0.f, 0.f, 0.f};
#pragma unroll
  for (int i = 0; i < 4; ++i)
#pragma unroll
    for (int j = 0; j < 4; ++j) acc[i][j] = z4;

  const int ar = t >> 1, ah = t & 1;
  const float* aptr = A + (size_t)(m0 + ar) * F + ah * 32;

  for (int k0 = 0; k0 < F; k0 += 64) {
    float4 v[8];
#pragma unroll
    for (int i = 0; i < 8; ++i)
      v[i] = *reinterpret_cast<const float4*>(aptr + k0 + 4 * i);
    uint32_t p[16];
#pragma unroll
    for (int i = 0; i < 8; ++i) {
      p[2 * i]     = pack_bf16_trunc(v[i].x, v[i].y);
      p[2 * i + 1] = pack_bf16_trunc(v[i].z, v[i].w);
    }
    int4* ldst = reinterpret_cast<int4*>(&lA[ar * 64 + ah * 32]);
#pragma unroll
    for (int i = 0; i < 4; ++i) ldst[i] = reinterpret_cast<const int4*>(p)[i];
#pragma unroll
    for (int c = 0; c < 4; ++c) {
      int chunk = w * 4 + c;
      gload_lds16(B + (size_t)(chunk * 8 + (lane >> 3)) * F + k0 + (lane & 7) * 8,
                  &lB[chunk * 512]);
    }
    __syncthreads();
#pragma unroll
    for (int ks = 0; ks < 2; ++ks) {
      bf16x8 af[4], bf[4];
#pragma unroll
      for (int i = 0; i < 4; ++i)
        af[i] = *reinterpret_cast<const bf16x8*>(&lA[(wr * 64 + i * 16 + fr) * 64 + ks * 32 + quad * 8]);
#pragma unroll
      for (int j = 0; j < 4; ++j)
        bf[j] = *reinterpret_cast<const bf16x8*>(&lB[(wc * 64 + j * 16 + fr) * 64 + ks * 32 + quad * 8]);
#pragma unroll
      for (int i = 0; i < 4; ++i)
#pragma unroll
        for (int j = 0; j < 4; ++j)
          acc[i][j] = __builtin_amdgcn_mfma_f32_16x16x32_bf16(af[i], bf[j], acc[i][j], 0, 0, 0);
    }
    __syncthreads();
  }
  u16* Pp = P + (size_t)h * M * 128;
#pragma unroll
  for (int i = 0; i < 4; ++i)
#pragma unroll
    for (int j = 0; j < 4; ++j) {
      int col = wc * 64 + j * 16 + fr;
      float bv = bias[h * 128 + col];
#pragma unroll
      for (int r = 0; r < 4; ++r) {
        int row = m0 + wr * 64 + i * 16 + quad * 4 + r;
        Pp[(size_t)row * 128 + col] = f2bf_rne(acc[i][j][r] + bv);
      }
    }
}

// ---------------------------------------------------------------------------
// colsum[h][m] = sum_n exp(SCALE * Sp[h][n].Kp[h][m]); grid (NK/128, H)
__global__ __launch_bounds__(256, 2) void sm_stats(
    const u16* __restrict__ Sp, const u16* __restrict__ Kp,
    float* __restrict__ colsum) {
  __shared__ u16 lA[128 * 128];  // Kp tile (m rows)
  __shared__ u16 lB[128 * 128];  // Sp tile (n rows)
  __shared__ float ls[128];
  const int h = blockIdx.y, m0 = blockIdx.x * 128;
  const u16* Kh = Kp + (size_t)h * NK_ * DH_;
  const u16* Sh = Sp + (size_t)h * NS_ * DH_;
  const int t = threadIdx.x, lane = t & 63, w = t >> 6;
  const int wr = w >> 1, wc = w & 1;
  const int fr = lane & 15, quad = lane >> 4;
  if (t < 128) ls[t] = 0.f;
#pragma unroll
  for (int c = 0; c < 8; ++c) {
    int chunk = w * 8 + c;
    gload_lds16(Kh + (size_t)(m0 + chunk * 4 + (lane >> 4)) * DH_ + (lane & 15) * 8,
                &lA[chunk * 512]);
  }
  __syncthreads();
  bf16x8 af[4][4];
#pragma unroll
  for (int i = 0; i < 4; ++i)
#pragma unroll
    for (int ks = 0; ks < 4; ++ks)
      af[i][ks] = *reinterpret_cast<const bf16x8*>(&lA[(wr * 64 + i * 16 + fr) * 128 + ks * 32 + quad * 8]);

  float part[4][4];
#pragma unroll
  for (int i = 0; i < 4; ++i)
#pragma unroll
    for (int r = 0; r < 4; ++r) part[i][r] = 0.f;

  const f32x4 z4 = {0.f, 0.f, 0.f, 0.f};
  for (int n0 = 0; n0 < NS_; n0 += 128) {
    __syncthreads();
#pragma unroll
    for (int c = 0; c < 8; ++c) {
      int chunk = w * 8 + c;
      gload_lds16(Sh + (size_t)(n0 + chunk * 4 + (lane >> 4)) * DH_ + (lane & 15) * 8,
                  &lB[chunk * 512]);
    }
    __syncthreads();
    f32x4 acc[4][4];
#pragma unroll
    for (int i = 0; i < 4; ++i)
#pragma unroll
      for (int j = 0; j < 4; ++j) acc[i][j] = z4;
#pragma unroll
    for (int ks = 0; ks < 4; ++ks) {
      bf16x8 bfr[4];
#pragma unroll
      for (int j = 0; j < 4; ++j)
        bfr[j] = *reinterpret_cast<const bf16x8*>(&lB[(wc * 64 + j * 16 + fr) * 128 + ks * 32 + quad * 8]);
#pragma unroll
      for (int i = 0; i < 4; ++i)
#pragma unroll
        for (int j = 0; j < 4; ++j)
          acc[i][j] = __builtin_amdgcn_mfma_f32_16x16x32_bf16(af[i][ks], bfr[j], acc[i][j], 0, 0, 0);
    }
#pragma unroll
    for (int i = 0; i < 4; ++i)
#pragma unroll
      for (int j = 0; j < 4; ++j)
#pragma unroll
        for (int r = 0; r < 4; ++r)
          part[i][r] += __expf(acc[i][j][r] * SCALE_);
  }
#pragma unroll
  for (int i = 0; i < 4; ++i)
#pragma unroll
    for (int r = 0; r < 4; ++r) {
      float v = part[i][r];
      v += __shfl_xor(v, 1); v += __shfl_xor(v, 2);
      v += __shfl_xor(v, 4); v += __shfl_xor(v, 8);
      part[i][r] = v;
    }
  if ((lane & 15) == 0) {
#pragma unroll
    for (int i = 0; i < 4; ++i)
#pragma unroll
      for (int r = 0; r < 4; ++r)
        atomicAdd(&ls[wr * 64 + i * 16 + quad * 4 + r], part[i][r]);
  }
  __syncthreads();
  if (t < 128) colsum[h * NK_ + m0 + t] = ls[t];
}

// ---------------------------------------------------------------------------
// attn[(h*NS+n)*NK+m] = exp(SCALE*s)/colsum[h][m]; grid (NK/128, NS/128, H)
__global__ __launch_bounds__(256, 2) void sm_attn(
    const u16* __restrict__ Sp, const u16* __restrict__ Kp,
    const float* __restrict__ colsum, float* __restrict__ attn) {
  __shared__ u16 lA[128 * 128];  // Sp tile (n rows)
  __shared__ u16 lB[128 * 128];  // Kp tile (m rows)
  const int h = blockIdx.z, m0 = blockIdx.x * 128, n0 = blockIdx.y * 128;
  const u16* Sh = Sp + (size_t)h * NS_ * DH_;
  const u16* Kh = Kp + (size_t)h * NK_ * DH_;
  const int t = threadIdx.x, lane = t & 63, w = t >> 6;
  const int wr = w >> 1, wc = w & 1;
  const int fr = lane & 15, quad = lane >> 4;
#pragma unroll
  for (int c = 0; c < 8; ++c) {
    int chunk = w * 8 + c;
    gload_lds16(Sh + (size_t)(n0 + chunk * 4 + (lane >> 4)) * DH_ + (lane & 15) * 8,
                &lA[chunk * 512]);
    gload_lds16(Kh + (size_t)(m0 + chunk * 4 + (lane >> 4)) * DH_ + (lane & 15) * 8,
                &lB[chunk * 512]);
  }
  __syncthreads();
  f32x4 acc[4][4];
  const f32x4 z4 = {0.f, 0.f, 0.f, 0.f};
#pragma unroll
  for (int i = 0; i < 4; ++i)
#pragma unroll
    for (int j = 0; j < 4; ++j) acc[i][j] = z4;
#pragma unroll
  for (int ks = 0; ks < 4; ++ks) {
    bf16x8 af[4], bf[4];
#pragma unroll
    for (int i = 0; i < 4; ++i)
      af[i] = *reinterpret_cast<const bf16x8*>(&lA[(wr * 64 + i * 16 + fr) * 128 + ks * 32 + quad * 8]);
#pragma unroll
    for (int j = 0; j < 4; ++j)
      bf[j] = *reinterpret_cast<const bf16x8*>(&lB[(wc * 64 + j * 16 + fr) * 128 + ks * 32 + quad * 8]);
#pragma unroll
    for (int i = 0; i < 4; ++i)
#pragma unroll
      for (int j = 0; j < 4; ++j)
        acc[i][j] = __builtin_amdgcn_mfma_f32_16x16x32_bf16(af[i], bf[j], acc[i][j], 0, 0, 0);
  }
#pragma unroll
  for (int j = 0; j < 4; ++j) {
    int m = m0 + wc * 64 + j * 16 + fr;
    float inv = 1.0f / colsum[h * NK_ + m];
#pragma unroll
    for (int i = 0; i < 4; ++i)
#pragma unroll
      for (int r = 0; r < 4; ++r) {
        int n = n0 + wr * 64 + i * 16 + quad * 4 + r;
        attn[((size_t)(h * NS_ + n)) * NK_ + m] = __expf(acc[i][j][r] * SCALE_) * inv;
      }
  }
}

// ---------------------------------------------------------------------------
// fused: C[R=16384][3072] = attn(fp32) @ Kt^T ; out2[n*24576 + h*3072 + f]
// grid (3072/128=24, 16384/128=128), block 256
__global__ __launch_bounds__(256, 2) void fused_gemm(
    const float* __restrict__ attn, const u16* __restrict__ Kt,
    float* __restrict__ out2) {
  __shared__ u16 lA[128 * 64];
  __shared__ u16 lB[128 * 64];
  const int f0 = blockIdx.x * 128, r0 = blockIdx.y * 128;
  const int t = threadIdx.x, lane = t & 63, w = t >> 6;
  const int wr = w >> 1, wc = w & 1;
  const int fr = lane & 15, quad = lane >> 4;
  f32x4 acc[4][4];
  const f32x4 z4 = {0.f, 0.f, 0.f, 0.f};
#pragma unroll
  for (int i = 0; i < 4; ++i)
#pragma unroll
    for (int j = 0; j < 4; ++j) acc[i][j] = z4;

  const int ar = t >> 1, ah = t & 1;
  const float* aptr = attn + (size_t)(r0 + ar) * NK_ + ah * 32;

  for (int k0 = 0; k0 < NK_; k0 += 64) {
    float4 v[8];
#pragma unroll
    for (int i = 0; i < 8; ++i)
      v[i] = *reinterpret_cast<const float4*>(aptr + k0 + 4 * i);
    uint32_t p[16];
#pragma unroll
    for (int i = 0; i < 8; ++i) {
      p[2 * i]     = pack_bf16_trunc(v[i].x, v[i].y);
      p[2 * i + 1] = pack_bf16_trunc(v[i].z, v[i].w);
    }
    int4* ldst = reinterpret_cast<int4*>(&lA[ar * 64 + ah * 32]);
#pragma unroll
    for (int i = 0; i < 4; ++i) ldst[i] = reinterpret_cast<const int4*>(p)[i];
#pragma unroll
    for (int c = 0; c < 4; ++c) {
      int chunk = w * 4 + c;
      gload_lds16(Kt + (size_t)(f0 + chunk * 8 + (lane >> 3)) * NK_ + k0 + (lane & 7) * 8,
                  &lB[chunk * 512]);
    }
    __syncthreads();
#pragma unroll
    for (int ks = 0; ks < 2; ++ks) {
      bf16x8 af[4], bf[4];
#pragma unroll
      for (int i = 0; i < 4; ++i)
        af[i] = *reinterpret_cast<const bf16x8*>(&lA[(wr * 64 + i * 16 + fr) * 64 + ks * 32 + quad * 8]);
#pragma unroll
      for (int j = 0; j < 4; ++j)
        bf[j] = *reinterpret_cast<const bf16x8*>(&lB[(wc * 64 + j * 16 + fr) * 64 + ks * 32 + quad * 8]);
#pragma unroll
      for (int i = 0; i < 4; ++i)
#pragma unroll
        for (int j = 0; j < 4; ++j)
          acc[i][j] = __builtin_amdgcn_mfma_f32_16x16x32_bf16(af[i], bf[j], acc[i][j], 0, 0, 0);
    }
    __syncthreads();
  }
#pragma unroll
  for (int i = 0; i < 4; ++i)
#pragma unroll
    for (int j = 0; j < 4; ++j)
#pragma unroll
      for (int r = 0; r < 4; ++r) {
        int R = r0 + wr * 64 + i * 16 + quad * 4 + r;
        int hh = R >> 11, n = R & 2047;
        int f = f0 + wc * 64 + j * 16 + fr;
        out2[(size_t)n * (H_ * KD_) + hh * KD_ + f] = acc[i][j][r];
      }
}

// ---------------------------------------------------------------------------
extern "C" void kernel_launch(void* const* d_in, const int* in_sizes, int n_in,
                              void* d_out, int out_size, void* d_ws, size_t ws_size,
                              hipStream_t stream) {
  const float* sentences = (const float*)d_in[0];
  const float* knowledge = (const float*)d_in[1];
  const float* w_s = (const float*)d_in[2];
  const float* b_s = (const float*)d_in[3];
  const float* w_k = (const float*)d_in[4];
  const float* b_k = (const float*)d_in[5];

  float* attn_out  = (float*)d_out;                          // [H*NS, NK] fp32
  float* fused_out = attn_out + (size_t)H_ * NS_ * NK_;      // [NS, H*KD] fp32

  // scratch hidden inside the fused-output region (written only by fused_gemm,
  // which reads none of it). 28.25 MB << 201 MB region.
  char* scr = (char*)fused_out;
  u16*   Kp     = (u16*)(scr);                           // 16 MB  [H][NK][DH] bf16
  u16*   Sp     = (u16*)(scr + 16u * 1024 * 1024);       //  4 MB  [H][NS][DH] bf16
  u16*   Wt_k   = (u16*)(scr + 20u * 1024 * 1024);       //  6 MB  [H][DH][KD] bf16
  u16*   Wt_s   = (u16*)(scr + 26u * 1024 * 1024);       //  2 MB  [H][DH][D]  bf16
  float* colsum = (float*)(scr + 28u * 1024 * 1024);     // 256 KB [H][NK] fp32
  u16*   Kt     = (u16*)d_ws;                            // 48 MB  [KD][NK] bf16

  transpose_cvt<<<dim3(D_ / 64, DH_ / 64, H_), 256, 0, stream>>>(w_s, Wt_s, D_, DH_);
  transpose_cvt<<<dim3(KD_ / 64, DH_ / 64, H_), 256, 0, stream>>>(w_k, Wt_k, KD_, DH_);
  transpose_cvt<<<dim3(NK_ / 64, KD_ / 64, 1), 256, 0, stream>>>(knowledge, Kt, NK_, KD_);

  proj_gemm<<<dim3(NS_ / 128, H_), 256, 0, stream>>>(sentences, Wt_s, b_s, Sp, NS_, D_);
  proj_gemm<<<dim3(NK_ / 128, H_), 256, 0, stream>>>(knowledge, Wt_k, b_k, Kp, NK_, KD_);

  sm_stats<<<dim3(NK_ / 128, H_), 256, 0, stream>>>(Sp, Kp, colsum);
  sm_attn<<<dim3(NK_ / 128, NS_ / 128, H_), 256, 0, stream>>>(Sp, Kp, colsum, attn_out);

  fused_gemm<<<dim3((H_ * KD_ / H_) / 128, (H_ * NS_) / 128), 256, 0, stream>>>(attn_out, Kt, fused_out);
}